// Round 1
// baseline (6087.942 us; speedup 1.0000x reference)
//
#include <hip/hip_runtime.h>

#define DIM 128
#define NLAB 1024
#define MT 64
#define LDK 136   // 128 + 8 pad: keeps 16B alignment, 2-way (free) LDS conflicts

typedef __bf16 bf16x4 __attribute__((ext_vector_type(4)));
typedef __bf16 bf16x8 __attribute__((ext_vector_type(8)));
typedef float  f32x4  __attribute__((ext_vector_type(4)));

// ---------------- scatter: agg[dst] += h[src], 32 threads/edge, float4 each
__global__ __launch_bounds__(256) void k_scatter(
    const float* __restrict__ h, const int* __restrict__ src,
    const int* __restrict__ dst, float* __restrict__ agg, int nE) {
  long long tid = (long long)blockIdx.x * 256 + threadIdx.x;
  int e = (int)(tid >> 5);
  if (e >= nE) return;
  int f = ((int)tid & 31) << 2;
  long long s = src[e], d = dst[e];
  const float4 v = *(const float4*)(h + s * DIM + f);
  float* a = agg + d * DIM + f;
  atomicAdd(a + 0, v.x);
  atomicAdd(a + 1, v.y);
  atomicAdd(a + 2, v.z);
  atomicAdd(a + 3, v.w);
}

// ---------------- GIN conv: hout = relu(((1+eps)*hin + agg) @ W + b)
__global__ __launch_bounds__(256) void k_gin_conv(
    const float* __restrict__ hin, const float* __restrict__ agg,
    const float* __restrict__ epsp, const float* __restrict__ W,
    const float* __restrict__ bias, float* __restrict__ hout, int n) {
  __shared__ __bf16 As[MT][LDK];
  __shared__ __bf16 Bs[DIM][LDK];
  const int t = threadIdx.x;
  const int rowBase = blockIdx.x * MT;
  const float e1 = 1.0f + epsp[0];

  // stage A: 64x128, x = (1+eps)*h + agg  -> bf16
#pragma unroll
  for (int it = 0; it < 8; ++it) {
    int idx = (it * 256 + t) << 2;
    int r = idx >> 7, c = idx & 127;
    int node = rowBase + r;
    float4 a4 = make_float4(0.f, 0.f, 0.f, 0.f);
    float4 g4 = a4;
    if (node < n) {
      a4 = *(const float4*)(hin + (size_t)node * DIM + c);
      g4 = *(const float4*)(agg + (size_t)node * DIM + c);
    }
    bf16x4 v;
    v[0] = (__bf16)(e1 * a4.x + g4.x);
    v[1] = (__bf16)(e1 * a4.y + g4.y);
    v[2] = (__bf16)(e1 * a4.z + g4.z);
    v[3] = (__bf16)(e1 * a4.w + g4.w);
    *(bf16x4*)&As[r][c] = v;
  }
  // stage B transposed: Bs[n][k] = W[k][n]; global reads coalesced over n
  {
    int nloc = t & 127;
    int kh = (t >> 7) << 6;
#pragma unroll
    for (int kk = 0; kk < 64; ++kk) {
      int k = kh + kk;
      Bs[nloc][k] = (__bf16)W[(size_t)k * DIM + nloc];
    }
  }
  __syncthreads();

  const int wv = t >> 6, lane = t & 63;
  const int quad = lane >> 4, l16 = lane & 15;
  f32x4 acc[4][2];
#pragma unroll
  for (int i = 0; i < 4; ++i) {
    acc[i][0] = f32x4{0.f, 0.f, 0.f, 0.f};
    acc[i][1] = f32x4{0.f, 0.f, 0.f, 0.f};
  }

#pragma unroll
  for (int kc = 0; kc < 4; ++kc) {
    int kb = kc * 32 + quad * 8;
    bf16x8 b0 = *(const bf16x8*)&Bs[wv * 32 + l16][kb];
    bf16x8 b1 = *(const bf16x8*)&Bs[wv * 32 + 16 + l16][kb];
#pragma unroll
    for (int rt = 0; rt < 4; ++rt) {
      bf16x8 a = *(const bf16x8*)&As[rt * 16 + l16][kb];
      acc[rt][0] = __builtin_amdgcn_mfma_f32_16x16x32_bf16(a, b0, acc[rt][0], 0, 0, 0);
      acc[rt][1] = __builtin_amdgcn_mfma_f32_16x16x32_bf16(a, b1, acc[rt][1], 0, 0, 0);
    }
  }

#pragma unroll
  for (int rt = 0; rt < 4; ++rt) {
#pragma unroll
    for (int ct = 0; ct < 2; ++ct) {
      int ncol = wv * 32 + ct * 16 + l16;
      float bv = bias[ncol];
#pragma unroll
      for (int r = 0; r < 4; ++r) {
        int node = rowBase + rt * 16 + quad * 4 + r;
        if (node < n) {
          float v = acc[rt][ct][r] + bv;
          hout[(size_t)node * DIM + ncol] = fmaxf(v, 0.f);
        }
      }
    }
  }
}

// ---------------- residual: out = hmid + relu(hmid @ rW + rb)   (hmid already relu'd)
__global__ __launch_bounds__(256) void k_residual(
    const float* __restrict__ hmid, const float* __restrict__ W,
    const float* __restrict__ bias, float* __restrict__ hout, int n) {
  __shared__ __bf16 As[MT][LDK];
  __shared__ __bf16 Bs[DIM][LDK];
  const int t = threadIdx.x;
  const int rowBase = blockIdx.x * MT;

#pragma unroll
  for (int it = 0; it < 8; ++it) {
    int idx = (it * 256 + t) << 2;
    int r = idx >> 7, c = idx & 127;
    int node = rowBase + r;
    float4 a4 = make_float4(0.f, 0.f, 0.f, 0.f);
    if (node < n) a4 = *(const float4*)(hmid + (size_t)node * DIM + c);
    bf16x4 v;
    v[0] = (__bf16)a4.x;
    v[1] = (__bf16)a4.y;
    v[2] = (__bf16)a4.z;
    v[3] = (__bf16)a4.w;
    *(bf16x4*)&As[r][c] = v;
  }
  {
    int nloc = t & 127;
    int kh = (t >> 7) << 6;
#pragma unroll
    for (int kk = 0; kk < 64; ++kk) {
      int k = kh + kk;
      Bs[nloc][k] = (__bf16)W[(size_t)k * DIM + nloc];
    }
  }
  __syncthreads();

  const int wv = t >> 6, lane = t & 63;
  const int quad = lane >> 4, l16 = lane & 15;
  f32x4 acc[4][2];
#pragma unroll
  for (int i = 0; i < 4; ++i) {
    acc[i][0] = f32x4{0.f, 0.f, 0.f, 0.f};
    acc[i][1] = f32x4{0.f, 0.f, 0.f, 0.f};
  }

#pragma unroll
  for (int kc = 0; kc < 4; ++kc) {
    int kb = kc * 32 + quad * 8;
    bf16x8 b0 = *(const bf16x8*)&Bs[wv * 32 + l16][kb];
    bf16x8 b1 = *(const bf16x8*)&Bs[wv * 32 + 16 + l16][kb];
#pragma unroll
    for (int rt = 0; rt < 4; ++rt) {
      bf16x8 a = *(const bf16x8*)&As[rt * 16 + l16][kb];
      acc[rt][0] = __builtin_amdgcn_mfma_f32_16x16x32_bf16(a, b0, acc[rt][0], 0, 0, 0);
      acc[rt][1] = __builtin_amdgcn_mfma_f32_16x16x32_bf16(a, b1, acc[rt][1], 0, 0, 0);
    }
  }

#pragma unroll
  for (int rt = 0; rt < 4; ++rt) {
#pragma unroll
    for (int ct = 0; ct < 2; ++ct) {
      int ncol = wv * 32 + ct * 16 + l16;
      float bv = bias[ncol];
#pragma unroll
      for (int r = 0; r < 4; ++r) {
        int node = rowBase + rt * 16 + quad * 4 + r;
        if (node < n) {
          float hv = hmid[(size_t)node * DIM + ncol];
          float v = fmaxf(acc[rt][ct][r] + bv, 0.f);
          hout[(size_t)node * DIM + ncol] = hv + v;
        }
      }
    }
  }
}

// ---------------- final: out = 0.5*(h1+h2) @ linW + linb
__global__ __launch_bounds__(256) void k_final(
    const float* __restrict__ h1, const float* __restrict__ h2,
    const float* __restrict__ W, const float* __restrict__ bias,
    float* __restrict__ out, int n) {
  __shared__ __bf16 As[MT][LDK];
  __shared__ __bf16 Bs[DIM][LDK];
  const int t = threadIdx.x;
  const int rowBase = blockIdx.x * MT;
  const int nb = blockIdx.y << 7;

#pragma unroll
  for (int it = 0; it < 8; ++it) {
    int idx = (it * 256 + t) << 2;
    int r = idx >> 7, c = idx & 127;
    int node = rowBase + r;
    float4 a4 = make_float4(0.f, 0.f, 0.f, 0.f);
    float4 b4 = a4;
    if (node < n) {
      a4 = *(const float4*)(h1 + (size_t)node * DIM + c);
      b4 = *(const float4*)(h2 + (size_t)node * DIM + c);
    }
    bf16x4 v;
    v[0] = (__bf16)(0.5f * (a4.x + b4.x));
    v[1] = (__bf16)(0.5f * (a4.y + b4.y));
    v[2] = (__bf16)(0.5f * (a4.z + b4.z));
    v[3] = (__bf16)(0.5f * (a4.w + b4.w));
    *(bf16x4*)&As[r][c] = v;
  }
  {
    int nloc = t & 127;
    int kh = (t >> 7) << 6;
#pragma unroll
    for (int kk = 0; kk < 64; ++kk) {
      int k = kh + kk;
      Bs[nloc][k] = (__bf16)W[(size_t)k * NLAB + nb + nloc];
    }
  }
  __syncthreads();

  const int wv = t >> 6, lane = t & 63;
  const int quad = lane >> 4, l16 = lane & 15;
  f32x4 acc[4][2];
#pragma unroll
  for (int i = 0; i < 4; ++i) {
    acc[i][0] = f32x4{0.f, 0.f, 0.f, 0.f};
    acc[i][1] = f32x4{0.f, 0.f, 0.f, 0.f};
  }

#pragma unroll
  for (int kc = 0; kc < 4; ++kc) {
    int kb = kc * 32 + quad * 8;
    bf16x8 b0 = *(const bf16x8*)&Bs[wv * 32 + l16][kb];
    bf16x8 b1 = *(const bf16x8*)&Bs[wv * 32 + 16 + l16][kb];
#pragma unroll
    for (int rt = 0; rt < 4; ++rt) {
      bf16x8 a = *(const bf16x8*)&As[rt * 16 + l16][kb];
      acc[rt][0] = __builtin_amdgcn_mfma_f32_16x16x32_bf16(a, b0, acc[rt][0], 0, 0, 0);
      acc[rt][1] = __builtin_amdgcn_mfma_f32_16x16x32_bf16(a, b1, acc[rt][1], 0, 0, 0);
    }
  }

#pragma unroll
  for (int rt = 0; rt < 4; ++rt) {
#pragma unroll
    for (int ct = 0; ct < 2; ++ct) {
      int ncol = wv * 32 + ct * 16 + l16;
      float bv = bias[nb + ncol];
#pragma unroll
      for (int r = 0; r < 4; ++r) {
        int node = rowBase + rt * 16 + quad * 4 + r;
        if (node < n) {
          out[(size_t)node * NLAB + nb + ncol] = acc[rt][ct][r] + bv;
        }
      }
    }
  }
}

extern "C" void kernel_launch(void* const* d_in, const int* in_sizes, int n_in,
                              void* d_out, int out_size, void* d_ws, size_t ws_size,
                              hipStream_t stream) {
  const float* inputs = (const float*)d_in[0];
  const int*   src    = (const int*)d_in[1];
  const int*   dst    = (const int*)d_in[2];
  const float* eps1   = (const float*)d_in[3];
  const float* W1     = (const float*)d_in[4];
  const float* b1     = (const float*)d_in[5];
  const float* rW1    = (const float*)d_in[6];
  const float* rb1    = (const float*)d_in[7];
  const float* eps2   = (const float*)d_in[8];
  const float* W2     = (const float*)d_in[9];
  const float* b2     = (const float*)d_in[10];
  const float* rW2    = (const float*)d_in[11];
  const float* rb2    = (const float*)d_in[12];
  const float* linW   = (const float*)d_in[13];
  const float* linb   = (const float*)d_in[14];
  float* out = (float*)d_out;

  const int n = in_sizes[0] / DIM;
  const int E = in_sizes[1];
  const size_t bufB = (size_t)n * DIM * sizeof(float);

  float* agg  = (float*)d_ws;                        // ws0 (later reused as h2)
  float* hmid = (float*)((char*)d_ws + bufB);        // ws1
  float* h1   = (float*)((char*)d_ws + 2 * bufB);    // ws2
  float* h2   = agg;                                 // ws0 reuse after conv2

  const int rowBlocks = (n + MT - 1) / MT;
  const int sBlocks = (int)(((long long)E * 32 + 255) / 256);
  dim3 fgrid(rowBlocks, NLAB / DIM);

  // layer 1
  hipMemsetAsync(agg, 0, bufB, stream);
  k_scatter<<<sBlocks, 256, 0, stream>>>(inputs, src, dst, agg, E);
  k_gin_conv<<<rowBlocks, 256, 0, stream>>>(inputs, agg, eps1, W1, b1, hmid, n);
  k_residual<<<rowBlocks, 256, 0, stream>>>(hmid, rW1, rb1, h1, n);
  // layer 2
  hipMemsetAsync(agg, 0, bufB, stream);
  k_scatter<<<sBlocks, 256, 0, stream>>>(h1, src, dst, agg, E);
  k_gin_conv<<<rowBlocks, 256, 0, stream>>>(h1, agg, eps2, W2, b2, hmid, n);
  k_residual<<<rowBlocks, 256, 0, stream>>>(hmid, rW2, rb2, h2, n);  // h2 -> ws0 (agg dead)
  // pooled head
  k_final<<<fgrid, 256, 0, stream>>>(h1, h2, linW, linb, out, n);
}

// Round 2
// 1706.227 us; speedup vs baseline: 3.5681x; 3.5681x over previous
//
#include <hip/hip_runtime.h>

#define DIM 128
#define NLAB 1024
#define MT 64
#define LDK 136   // 128 + 8 pad: keeps 16B alignment, 2-way (free) LDS conflicts

typedef __bf16 bf16x4 __attribute__((ext_vector_type(4)));
typedef __bf16 bf16x8 __attribute__((ext_vector_type(8)));
typedef float  f32x4  __attribute__((ext_vector_type(4)));

// ---------------- CSR build step 1: histogram of dst
__global__ __launch_bounds__(256) void k_hist(
    const int* __restrict__ dst, int* __restrict__ cnt, int nE) {
  int e = blockIdx.x * 256 + threadIdx.x;
  if (e < nE) atomicAdd(&cnt[dst[e]], 1);
}

// ---------------- CSR build step 2: exclusive scan (single block, 1024 thr)
// reads cnt, writes off[0..n] and cur[0..n-1] (cur may alias cnt)
__global__ __launch_bounds__(1024) void k_scan(
    const int* __restrict__ cnt, int* __restrict__ off,
    int* __restrict__ cur, int n) {
  __shared__ int part[1024];
  const int t = threadIdx.x;
  const int per = (n + 1023) >> 10;
  const int start = t * per;
  const int end = min(start + per, n);
  int s = 0;
  for (int i = start; i < end; ++i) s += cnt[i];
  part[t] = s;
  __syncthreads();
  for (int d = 1; d < 1024; d <<= 1) {
    int v = (t >= d) ? part[t - d] : 0;
    __syncthreads();
    part[t] += v;
    __syncthreads();
  }
  int excl = (t == 0) ? 0 : part[t - 1];
  if (t == 1023) off[n] = part[1023];
  for (int i = start; i < end; ++i) {
    int c = cnt[i];          // read before cur write: cur may alias cnt
    off[i] = excl;
    cur[i] = excl;
    excl += c;
  }
}

// ---------------- CSR build step 3: fill bins with src ids (sorted by dst)
__global__ __launch_bounds__(256) void k_binfill(
    const int* __restrict__ src, const int* __restrict__ dst,
    int* __restrict__ cur, int* __restrict__ eidx, int nE) {
  int e = blockIdx.x * 256 + threadIdx.x;
  if (e < nE) {
    int p = atomicAdd(&cur[dst[e]], 1);
    eidx[p] = src[e];
  }
}

// ---------------- gather-aggregate: agg[d,:] = sum_{s in N(d)} h[s,:]
// 128 threads per node (one feature each), 2 nodes per block
__global__ __launch_bounds__(256) void k_gather(
    const float* __restrict__ h, const int* __restrict__ off,
    const int* __restrict__ eidx, float* __restrict__ agg, int n) {
  int node = blockIdx.x * 2 + (threadIdx.x >> 7);
  if (node >= n) return;
  int f = threadIdx.x & 127;
  int beg = off[node], end = off[node + 1];
  float acc = 0.f;
  for (int e = beg; e < end; ++e) {
    int s = eidx[e];
    acc += h[(size_t)s * DIM + f];
  }
  agg[(size_t)node * DIM + f] = acc;
}

// ---------------- GIN conv: hout = relu(((1+eps)*hin + agg) @ W + b)
__global__ __launch_bounds__(256) void k_gin_conv(
    const float* __restrict__ hin, const float* __restrict__ agg,
    const float* __restrict__ epsp, const float* __restrict__ W,
    const float* __restrict__ bias, float* __restrict__ hout, int n) {
  __shared__ __bf16 As[MT][LDK];
  __shared__ __bf16 Bs[DIM][LDK];
  const int t = threadIdx.x;
  const int rowBase = blockIdx.x * MT;
  const float e1 = 1.0f + epsp[0];

#pragma unroll
  for (int it = 0; it < 8; ++it) {
    int idx = (it * 256 + t) << 2;
    int r = idx >> 7, c = idx & 127;
    int node = rowBase + r;
    float4 a4 = make_float4(0.f, 0.f, 0.f, 0.f);
    float4 g4 = a4;
    if (node < n) {
      a4 = *(const float4*)(hin + (size_t)node * DIM + c);
      g4 = *(const float4*)(agg + (size_t)node * DIM + c);
    }
    bf16x4 v;
    v[0] = (__bf16)(e1 * a4.x + g4.x);
    v[1] = (__bf16)(e1 * a4.y + g4.y);
    v[2] = (__bf16)(e1 * a4.z + g4.z);
    v[3] = (__bf16)(e1 * a4.w + g4.w);
    *(bf16x4*)&As[r][c] = v;
  }
  {
    int nloc = t & 127;
    int kh = (t >> 7) << 6;
#pragma unroll
    for (int kk = 0; kk < 64; ++kk) {
      int k = kh + kk;
      Bs[nloc][k] = (__bf16)W[(size_t)k * DIM + nloc];
    }
  }
  __syncthreads();

  const int wv = t >> 6, lane = t & 63;
  const int quad = lane >> 4, l16 = lane & 15;
  f32x4 acc[4][2];
#pragma unroll
  for (int i = 0; i < 4; ++i) {
    acc[i][0] = f32x4{0.f, 0.f, 0.f, 0.f};
    acc[i][1] = f32x4{0.f, 0.f, 0.f, 0.f};
  }

#pragma unroll
  for (int kc = 0; kc < 4; ++kc) {
    int kb = kc * 32 + quad * 8;
    bf16x8 b0 = *(const bf16x8*)&Bs[wv * 32 + l16][kb];
    bf16x8 b1 = *(const bf16x8*)&Bs[wv * 32 + 16 + l16][kb];
#pragma unroll
    for (int rt = 0; rt < 4; ++rt) {
      bf16x8 a = *(const bf16x8*)&As[rt * 16 + l16][kb];
      acc[rt][0] = __builtin_amdgcn_mfma_f32_16x16x32_bf16(a, b0, acc[rt][0], 0, 0, 0);
      acc[rt][1] = __builtin_amdgcn_mfma_f32_16x16x32_bf16(a, b1, acc[rt][1], 0, 0, 0);
    }
  }

#pragma unroll
  for (int rt = 0; rt < 4; ++rt) {
#pragma unroll
    for (int ct = 0; ct < 2; ++ct) {
      int ncol = wv * 32 + ct * 16 + l16;
      float bv = bias[ncol];
#pragma unroll
      for (int r = 0; r < 4; ++r) {
        int node = rowBase + rt * 16 + quad * 4 + r;
        if (node < n) {
          float v = acc[rt][ct][r] + bv;
          hout[(size_t)node * DIM + ncol] = fmaxf(v, 0.f);
        }
      }
    }
  }
}

// ---------------- residual: out = hmid + relu(hmid @ rW + rb)
__global__ __launch_bounds__(256) void k_residual(
    const float* __restrict__ hmid, const float* __restrict__ W,
    const float* __restrict__ bias, float* __restrict__ hout, int n) {
  __shared__ __bf16 As[MT][LDK];
  __shared__ __bf16 Bs[DIM][LDK];
  const int t = threadIdx.x;
  const int rowBase = blockIdx.x * MT;

#pragma unroll
  for (int it = 0; it < 8; ++it) {
    int idx = (it * 256 + t) << 2;
    int r = idx >> 7, c = idx & 127;
    int node = rowBase + r;
    float4 a4 = make_float4(0.f, 0.f, 0.f, 0.f);
    if (node < n) a4 = *(const float4*)(hmid + (size_t)node * DIM + c);
    bf16x4 v;
    v[0] = (__bf16)a4.x;
    v[1] = (__bf16)a4.y;
    v[2] = (__bf16)a4.z;
    v[3] = (__bf16)a4.w;
    *(bf16x4*)&As[r][c] = v;
  }
  {
    int nloc = t & 127;
    int kh = (t >> 7) << 6;
#pragma unroll
    for (int kk = 0; kk < 64; ++kk) {
      int k = kh + kk;
      Bs[nloc][k] = (__bf16)W[(size_t)k * DIM + nloc];
    }
  }
  __syncthreads();

  const int wv = t >> 6, lane = t & 63;
  const int quad = lane >> 4, l16 = lane & 15;
  f32x4 acc[4][2];
#pragma unroll
  for (int i = 0; i < 4; ++i) {
    acc[i][0] = f32x4{0.f, 0.f, 0.f, 0.f};
    acc[i][1] = f32x4{0.f, 0.f, 0.f, 0.f};
  }

#pragma unroll
  for (int kc = 0; kc < 4; ++kc) {
    int kb = kc * 32 + quad * 8;
    bf16x8 b0 = *(const bf16x8*)&Bs[wv * 32 + l16][kb];
    bf16x8 b1 = *(const bf16x8*)&Bs[wv * 32 + 16 + l16][kb];
#pragma unroll
    for (int rt = 0; rt < 4; ++rt) {
      bf16x8 a = *(const bf16x8*)&As[rt * 16 + l16][kb];
      acc[rt][0] = __builtin_amdgcn_mfma_f32_16x16x32_bf16(a, b0, acc[rt][0], 0, 0, 0);
      acc[rt][1] = __builtin_amdgcn_mfma_f32_16x16x32_bf16(a, b1, acc[rt][1], 0, 0, 0);
    }
  }

#pragma unroll
  for (int rt = 0; rt < 4; ++rt) {
#pragma unroll
    for (int ct = 0; ct < 2; ++ct) {
      int ncol = wv * 32 + ct * 16 + l16;
      float bv = bias[ncol];
#pragma unroll
      for (int r = 0; r < 4; ++r) {
        int node = rowBase + rt * 16 + quad * 4 + r;
        if (node < n) {
          float hv = hmid[(size_t)node * DIM + ncol];
          float v = fmaxf(acc[rt][ct][r] + bv, 0.f);
          hout[(size_t)node * DIM + ncol] = hv + v;
        }
      }
    }
  }
}

// ---------------- final: out = 0.5*(h1+h2) @ linW + linb
__global__ __launch_bounds__(256) void k_final(
    const float* __restrict__ h1, const float* __restrict__ h2,
    const float* __restrict__ W, const float* __restrict__ bias,
    float* __restrict__ out, int n) {
  __shared__ __bf16 As[MT][LDK];
  __shared__ __bf16 Bs[DIM][LDK];
  const int t = threadIdx.x;
  const int rowBase = blockIdx.x * MT;
  const int nb = blockIdx.y << 7;

#pragma unroll
  for (int it = 0; it < 8; ++it) {
    int idx = (it * 256 + t) << 2;
    int r = idx >> 7, c = idx & 127;
    int node = rowBase + r;
    float4 a4 = make_float4(0.f, 0.f, 0.f, 0.f);
    float4 b4 = a4;
    if (node < n) {
      a4 = *(const float4*)(h1 + (size_t)node * DIM + c);
      b4 = *(const float4*)(h2 + (size_t)node * DIM + c);
    }
    bf16x4 v;
    v[0] = (__bf16)(0.5f * (a4.x + b4.x));
    v[1] = (__bf16)(0.5f * (a4.y + b4.y));
    v[2] = (__bf16)(0.5f * (a4.z + b4.z));
    v[3] = (__bf16)(0.5f * (a4.w + b4.w));
    *(bf16x4*)&As[r][c] = v;
  }
  {
    int nloc = t & 127;
    int kh = (t >> 7) << 6;
#pragma unroll
    for (int kk = 0; kk < 64; ++kk) {
      int k = kh + kk;
      Bs[nloc][k] = (__bf16)W[(size_t)k * NLAB + nb + nloc];
    }
  }
  __syncthreads();

  const int wv = t >> 6, lane = t & 63;
  const int quad = lane >> 4, l16 = lane & 15;
  f32x4 acc[4][2];
#pragma unroll
  for (int i = 0; i < 4; ++i) {
    acc[i][0] = f32x4{0.f, 0.f, 0.f, 0.f};
    acc[i][1] = f32x4{0.f, 0.f, 0.f, 0.f};
  }

#pragma unroll
  for (int kc = 0; kc < 4; ++kc) {
    int kb = kc * 32 + quad * 8;
    bf16x8 b0 = *(const bf16x8*)&Bs[wv * 32 + l16][kb];
    bf16x8 b1 = *(const bf16x8*)&Bs[wv * 32 + 16 + l16][kb];
#pragma unroll
    for (int rt = 0; rt < 4; ++rt) {
      bf16x8 a = *(const bf16x8*)&As[rt * 16 + l16][kb];
      acc[rt][0] = __builtin_amdgcn_mfma_f32_16x16x32_bf16(a, b0, acc[rt][0], 0, 0, 0);
      acc[rt][1] = __builtin_amdgcn_mfma_f32_16x16x32_bf16(a, b1, acc[rt][1], 0, 0, 0);
    }
  }

#pragma unroll
  for (int rt = 0; rt < 4; ++rt) {
#pragma unroll
    for (int ct = 0; ct < 2; ++ct) {
      int ncol = wv * 32 + ct * 16 + l16;
      float bv = bias[nb + ncol];
#pragma unroll
      for (int r = 0; r < 4; ++r) {
        int node = rowBase + rt * 16 + quad * 4 + r;
        if (node < n) {
          out[(size_t)node * NLAB + nb + ncol] = acc[rt][ct][r] + bv;
        }
      }
    }
  }
}

extern "C" void kernel_launch(void* const* d_in, const int* in_sizes, int n_in,
                              void* d_out, int out_size, void* d_ws, size_t ws_size,
                              hipStream_t stream) {
  const float* inputs = (const float*)d_in[0];
  const int*   src    = (const int*)d_in[1];
  const int*   dst    = (const int*)d_in[2];
  const float* eps1   = (const float*)d_in[3];
  const float* W1     = (const float*)d_in[4];
  const float* b1     = (const float*)d_in[5];
  const float* rW1    = (const float*)d_in[6];
  const float* rb1    = (const float*)d_in[7];
  const float* eps2   = (const float*)d_in[8];
  const float* W2     = (const float*)d_in[9];
  const float* b2     = (const float*)d_in[10];
  const float* rW2    = (const float*)d_in[11];
  const float* rb2    = (const float*)d_in[12];
  const float* linW   = (const float*)d_in[13];
  const float* linb   = (const float*)d_in[14];
  float* out = (float*)d_out;

  const int n = in_sizes[0] / DIM;
  const int E = in_sizes[1];
  const size_t bufB = (size_t)n * DIM * sizeof(float);

  // node-feature scratch in d_ws
  float* agg  = (float*)d_ws;                        // ws0 (reused as h2)
  float* hmid = (float*)((char*)d_ws + bufB);        // ws1
  float* h1   = (float*)((char*)d_ws + 2 * bufB);    // ws2
  float* h2   = agg;

  // CSR scratch lives in d_out (409.6 MB; dead until k_final, stream-ordered)
  int* eidx = (int*)d_out;          // E ints
  int* off  = eidx + E;             // n+1 ints
  int* cur  = off + (n + 1);        // n ints (doubles as histogram cnt)

  const int rowBlocks = (n + MT - 1) / MT;
  const int eBlocks = (E + 255) / 256;
  const int gBlocks = (n + 1) / 2;
  dim3 fgrid(rowBlocks, NLAB / DIM);

  // ---- build CSR once (shared by both layers)
  hipMemsetAsync(cur, 0, (size_t)n * sizeof(int), stream);
  k_hist<<<eBlocks, 256, 0, stream>>>(dst, cur, E);
  k_scan<<<1, 1024, 0, stream>>>(cur, off, cur, n);
  k_binfill<<<eBlocks, 256, 0, stream>>>(src, dst, cur, eidx, E);

  // ---- layer 1
  k_gather<<<gBlocks, 256, 0, stream>>>(inputs, off, eidx, agg, n);
  k_gin_conv<<<rowBlocks, 256, 0, stream>>>(inputs, agg, eps1, W1, b1, hmid, n);
  k_residual<<<rowBlocks, 256, 0, stream>>>(hmid, rW1, rb1, h1, n);
  // ---- layer 2
  k_gather<<<gBlocks, 256, 0, stream>>>(h1, off, eidx, agg, n);
  k_gin_conv<<<rowBlocks, 256, 0, stream>>>(h1, agg, eps2, W2, b2, hmid, n);
  k_residual<<<rowBlocks, 256, 0, stream>>>(hmid, rW2, rb2, h2, n);
  // ---- pooled head (reads h1,h2; overwrites all of d_out incl. CSR scratch)
  k_final<<<fgrid, 256, 0, stream>>>(h1, h2, linW, linb, out, n);
}